// Round 11
// baseline (1512.897 us; speedup 1.0000x reference)
//
#include <hip/hip_runtime.h>
#include <hip/hip_bf16.h>
#include <stdint.h>

// out[b,o] = sum_i x[b,i]*(bw[o,i] + dwb[o,i] + T[b,i]) + bbias[o] + dbb[o] + dot(z[b,:], dbW[o,:])
//   where T[b,i] = sum_k z[b,k] * dwW[o*IN + i, k]
//
// One block per output column o. The block streams dwW rows [o*IN, o*IN+IN) --
// a CONTIGUOUS 512 KB slab -- exactly once (global->reg->bf16 via nontemporal
// loads, 2-deep named register double-buffer, no barriers in the hot loop).
//
// MFMA operand order: A = dwW fragment (M = i-tile rows), B = z fragment
// (N = b). A/B fragments share the same per-lane layout (non-K idx = lane&15,
// k = (lane>>4)*8+j), so this is data-identical to mfma(z,dwW) but flips C/D
// to col=b(l16), row=i_local(q*4+r): the x-fold then reads x[b][4 consecutive
// i] as ONE float4 (vs 32 scalar stride-4KB loads), and bw+dwb come from a
// 4 KB LDS stage as a broadcast float4. Fold stays fp32. Reduction over i:
// sum 4 rows in-lane, then shfl_xor(16,32) across q-groups, then LDS across
// waves. No split-K, no atomics, single kernel; out is pure-write
// (idempotent under graph replay).
//
// r9 fix: __builtin_nontemporal_load requires a native vector type --
// HIP's float4 (HIP_vector_type) is a class and is rejected. Stream buffers
// bregA/bregB are now f32x4 (ext_vector_type), indexed [0..3]. All other
// vector-builtin uses (f32x4 splat, MFMA args) already ext-vector and
// present in the prior harness-verified kernel.
// HBM floor = 512 MB (dwW once) / 6.3 TB/s ~ 83 us -> memory-bound.

#define IN_N  1024
#define OUT_N 1024
#define ZD_N  128
#define B_N   128

typedef __attribute__((ext_vector_type(8))) short s16x8;  // 8 bf16 (4 VGPRs)
typedef __attribute__((ext_vector_type(4))) float f32x4;

__global__ __launch_bounds__(256, 2) void hyper_fused(
    const float* __restrict__ x,     // [128,1024]
    const float* __restrict__ z,     // [128,128]
    const float* __restrict__ bw,    // [1024,1024]
    const float* __restrict__ dwW,   // [1024*1024,128] row-major, K contiguous
    const float* __restrict__ dwb,   // [1024*1024] viewed as [1024,1024]
    const float* __restrict__ bbias, // [1024]
    const float* __restrict__ dbW,   // [1024,128]
    const float* __restrict__ dbb,   // [1024]
    float* __restrict__ out)         // [128,1024]
{
    __shared__ s16x8 zlds[16 * 128];  // [k-granule g = k/8][b], bf16, 32 KB
    __shared__ float wlds[IN_N];      // bw[o,:] + dwb[o,:], fp32, 4 KB
    __shared__ float red[4][B_N];     // per-wave partial sums over i

    const int tid  = threadIdx.x;
    const int lane = tid & 63;
    const int w    = tid >> 6;   // wave 0..3
    const int q    = lane >> 4;
    const int l16  = lane & 15;
    const int o    = blockIdx.x;

    // ---- stage z -> LDS bf16, [g][b] layout (conflict-free ds_read_b128)
    {
        const int m  = tid & 127;
        const int g0 = (tid >> 7) * 8;  // this thread's 8 granules
        const float* zr = z + (size_t)m * ZD_N + g0 * 8;
#pragma unroll
        for (int j = 0; j < 8; ++j) {
            float4 a = *(const float4*)(zr + j * 8);
            float4 b = *(const float4*)(zr + j * 8 + 4);
            union { s16x8 v; __hip_bfloat162 b2[4]; } u;
            u.b2[0] = __float22bfloat162_rn(make_float2(a.x, a.y));
            u.b2[1] = __float22bfloat162_rn(make_float2(a.z, a.w));
            u.b2[2] = __float22bfloat162_rn(make_float2(b.x, b.y));
            u.b2[3] = __float22bfloat162_rn(make_float2(b.z, b.w));
            zlds[(g0 + j) * 128 + m] = u.v;
        }
    }
    // ---- stage wsum = bw[o,:] + dwb[o,:] -> LDS fp32 (coalesced float4)
    {
        float4 a = *(const float4*)(bw  + (size_t)o * IN_N + tid * 4);
        float4 b = *(const float4*)(dwb + (size_t)o * IN_N + tid * 4);
        *(float4*)&wlds[tid * 4] =
            make_float4(a.x + b.x, a.y + b.y, a.z + b.z, a.w + b.w);
    }
    __syncthreads();

    // ---- main loop: wave w owns i in [w*256, (w+1)*256), 16 tiles of 16 i.
    // Stream fragment: lane reads dwW row (o*IN + ibase + it*16 + l16), k-bytes
    // [q*32, q*32+32) per K=32 step -> the wave sweeps a contiguous aligned
    // 8 KB block per i-tile, exactly once.
    const int ibase = w * 256;
    const float* lp = dwW + (size_t)o * IN_N * ZD_N + (size_t)(ibase + l16) * ZD_N + q * 8;

    float pt[8][4];   // [bt][r]: partial over i, b = bt*16 + l16, i-row r
#pragma unroll
    for (int bt = 0; bt < 8; ++bt)
#pragma unroll
        for (int r = 0; r < 4; ++r) pt[bt][r] = 0.f;

    // Two named prefetch buffers (static indexing only -- rule #20): load for
    // tile t+2 is issued while tile t computes (~2 tiles of latency cover).
    // f32x4 (ext_vector_type), NOT float4: nontemporal builtin requires a
    // native vector type.
    f32x4 bregA[8], bregB[8];
#define LOADI(DST, IT)                                                          \
    {                                                                           \
        const float* p_ = lp + (size_t)(IT) * (16 * ZD_N);                      \
        _Pragma("unroll") for (int s = 0; s < 4; ++s) {                         \
            DST[s * 2 + 0] =                                                    \
                __builtin_nontemporal_load((const f32x4*)(p_ + s * 32));        \
            DST[s * 2 + 1] =                                                    \
                __builtin_nontemporal_load((const f32x4*)(p_ + s * 32 + 4));    \
        }                                                                       \
    }

#define STEP(BUF, IT, PF)                                                       \
    {                                                                           \
        s16x8 bfr[4];                                                           \
        _Pragma("unroll") for (int s = 0; s < 4; ++s) {                         \
            union { s16x8 v; __hip_bfloat162 b2[4]; } u;                        \
            u.b2[0] = __float22bfloat162_rn(                                    \
                make_float2(BUF[s * 2][0], BUF[s * 2][1]));                     \
            u.b2[1] = __float22bfloat162_rn(                                    \
                make_float2(BUF[s * 2][2], BUF[s * 2][3]));                     \
            u.b2[2] = __float22bfloat162_rn(                                    \
                make_float2(BUF[s * 2 + 1][0], BUF[s * 2 + 1][1]));             \
            u.b2[3] = __float22bfloat162_rn(                                    \
                make_float2(BUF[s * 2 + 1][2], BUF[s * 2 + 1][3]));             \
            bfr[s] = u.v;                                                       \
        }                                                                       \
        if (PF) LOADI(BUF, (IT) + 2);   /* overwrite only after cvt consumed */ \
        const int i0 = ibase + (IT) * 16 + q * 4;  /* this lane's C/D rows   */ \
        float4 wsv = *(const float4*)&wlds[i0];    /* broadcast within q-grp */ \
        f32x4 acc[8];                                                           \
        _Pragma("unroll") for (int bt = 0; bt < 8; ++bt) acc[bt] = (f32x4)0.0f; \
        _Pragma("unroll") for (int s = 0; s < 4; ++s) {                         \
            const s16x8* zp = &zlds[(s * 4 + q) * 128 + l16];                   \
            _Pragma("unroll") for (int bt = 0; bt < 8; ++bt)                    \
                acc[bt] = __builtin_amdgcn_mfma_f32_16x16x32_bf16(              \
                    bfr[s], zp[bt * 16], acc[bt], 0, 0, 0);                     \
        }                                                                       \
        /* C/D: col = l16 (= b, +bt*16), row = q*4 + r (= i_local).          */ \
        /* fp32 fold: pt += (T + bw + dwb) * x, x as one float4 per bt.      */ \
        _Pragma("unroll") for (int bt = 0; bt < 8; ++bt) {                      \
            float4 xv = *(const float4*)(x + (size_t)(bt * 16 + l16) * IN_N + i0); \
            pt[bt][0] += (acc[bt][0] + wsv.x) * xv.x;                           \
            pt[bt][1] += (acc[bt][1] + wsv.y) * xv.y;                           \
            pt[bt][2] += (acc[bt][2] + wsv.z) * xv.z;                           \
            pt[bt][3] += (acc[bt][3] + wsv.w) * xv.w;                           \
        }                                                                       \
    }

    LOADI(bregA, 0);
    LOADI(bregB, 1);
#pragma unroll
    for (int it2 = 0; it2 < 8; ++it2) {
        STEP(bregA, it2 * 2,     it2 < 7);
        STEP(bregB, it2 * 2 + 1, it2 < 7);
    }
#undef STEP
#undef LOADI

    // ---- reduce over i: sum the 4 rows in-lane, then across q-groups
#pragma unroll
    for (int bt = 0; bt < 8; ++bt) {
        float s = pt[bt][0] + pt[bt][1] + pt[bt][2] + pt[bt][3];
        s += __shfl_xor(s, 16, 64);
        s += __shfl_xor(s, 32, 64);
        if (lane < 16) red[w][bt * 16 + l16] = s;
    }
    __syncthreads();

    // ---- cross-wave combine + small terms (fp32 exact), one thread per b
    if (tid < B_N) {
        const int b = tid;
        float s = red[0][b] + red[1][b] + red[2][b] + red[3][b]
                + bbias[o] + dbb[o];
        const float* zr = z + (size_t)b * ZD_N;
        const float* dr = dbW + (size_t)o * ZD_N;
#pragma unroll 8
        for (int k = 0; k < ZD_N; k += 4) {
            float4 zv = *(const float4*)(zr + k);
            float4 dv = *(const float4*)(dr + k);
            s += zv.x * dv.x + zv.y * dv.y + zv.z * dv.z + zv.w * dv.w;
        }
        out[(size_t)b * OUT_N + o] = s;
    }
}

extern "C" void kernel_launch(void* const* d_in, const int* in_sizes, int n_in,
                              void* d_out, int out_size, void* d_ws, size_t ws_size,
                              hipStream_t stream) {
    hipLaunchKernelGGL(hyper_fused, dim3(OUT_N), dim3(256), 0, stream,
                       (const float*)d_in[0],  // x
                       (const float*)d_in[1],  // z
                       (const float*)d_in[2],  // base_weight
                       (const float*)d_in[3],  // dw_W
                       (const float*)d_in[4],  // dw_b
                       (const float*)d_in[5],  // base_bias
                       (const float*)d_in[6],  // db_W
                       (const float*)d_in[7],  // db_b
                       (float*)d_out);
}

// Round 12
// 778.316 us; speedup vs baseline: 1.9438x; 1.9438x over previous
//
#include <hip/hip_runtime.h>
#include <hip/hip_bf16.h>
#include <stdint.h>

// out[b,o] = sum_i x[b,i]*(bw[o,i] + dwb[o,i] + T[b,i]) + bbias[o] + dbb[o] + dot(z[b,:], dbW[o,:])
//   where T[b,i] = sum_k z[b,k] * dwW[o*IN + i, k]
//
// One block per output column o; streams the contiguous 512 KB dwW slab once.
//
// r11 post-mortem: WRITE_SIZE=1.68GB + FETCH=1.32GB at VGPR_Count=128 =>
// register SPILLS to scratch (live set ~190 with 2-deep dbuf + pt[8][4]).
// Fix: (1) single breg buffer, prefetch-after-convert (-32 VGPR);
// (2) fold the 4-row x-product into pt[bt] scalar accumulators (32->8 VGPR).
// Live set now ~100 <= 128 budget -> no scratch. launch_bounds(256) lets
// occupancy reach the LDS-implied 4 blocks/CU (38.9 KB LDS).
// HBM floor = 512 MB / 6.3 TB/s ~ 83 us -> memory-bound.

#define IN_N  1024
#define OUT_N 1024
#define ZD_N  128
#define B_N   128

typedef __attribute__((ext_vector_type(8))) short s16x8;  // 8 bf16 (4 VGPRs)
typedef __attribute__((ext_vector_type(4))) float f32x4;

__global__ __launch_bounds__(256) void hyper_fused(
    const float* __restrict__ x,     // [128,1024]
    const float* __restrict__ z,     // [128,128]
    const float* __restrict__ bw,    // [1024,1024]
    const float* __restrict__ dwW,   // [1024*1024,128] row-major, K contiguous
    const float* __restrict__ dwb,   // [1024*1024] viewed as [1024,1024]
    const float* __restrict__ bbias, // [1024]
    const float* __restrict__ dbW,   // [1024,128]
    const float* __restrict__ dbb,   // [1024]
    float* __restrict__ out)         // [128,1024]
{
    __shared__ s16x8 zlds[16 * 128];  // [k-granule g = k/8][b], bf16, 32 KB
    __shared__ float wlds[IN_N];      // bw[o,:] + dwb[o,:], fp32, 4 KB
    __shared__ float red[4][B_N];     // per-wave partial sums over i

    const int tid  = threadIdx.x;
    const int lane = tid & 63;
    const int w    = tid >> 6;   // wave 0..3
    const int q    = lane >> 4;
    const int l16  = lane & 15;
    const int o    = blockIdx.x;

    // ---- stage z -> LDS bf16, [g][b] layout (conflict-free ds_read_b128)
    {
        const int m  = tid & 127;
        const int g0 = (tid >> 7) * 8;  // this thread's 8 granules
        const float* zr = z + (size_t)m * ZD_N + g0 * 8;
#pragma unroll
        for (int j = 0; j < 8; ++j) {
            float4 a = *(const float4*)(zr + j * 8);
            float4 b = *(const float4*)(zr + j * 8 + 4);
            union { s16x8 v; __hip_bfloat162 b2[4]; } u;
            u.b2[0] = __float22bfloat162_rn(make_float2(a.x, a.y));
            u.b2[1] = __float22bfloat162_rn(make_float2(a.z, a.w));
            u.b2[2] = __float22bfloat162_rn(make_float2(b.x, b.y));
            u.b2[3] = __float22bfloat162_rn(make_float2(b.z, b.w));
            zlds[(g0 + j) * 128 + m] = u.v;
        }
    }
    // ---- stage wsum = bw[o,:] + dwb[o,:] -> LDS fp32 (coalesced float4)
    {
        float4 a = *(const float4*)(bw  + (size_t)o * IN_N + tid * 4);
        float4 b = *(const float4*)(dwb + (size_t)o * IN_N + tid * 4);
        *(float4*)&wlds[tid * 4] =
            make_float4(a.x + b.x, a.y + b.y, a.z + b.z, a.w + b.w);
    }
    __syncthreads();

    // ---- main loop: wave w owns i in [w*256, (w+1)*256), 16 tiles of 16 i.
    // Per tile the wave sweeps a contiguous aligned 8 KB block of dwW, once.
    const int ibase = w * 256;
    const float* lp = dwW + (size_t)o * IN_N * ZD_N + (size_t)(ibase + l16) * ZD_N + q * 8;

    float pt[8];      // [bt]: partial over i for b = bt*16 + l16
#pragma unroll
    for (int bt = 0; bt < 8; ++bt) pt[bt] = 0.f;

    // Single prefetch buffer (static indexing only -- rule #20): next tile's
    // loads are issued right after the current tile's cvt consumes breg.
    f32x4 breg[8];
#define LOADI(IT)                                                               \
    {                                                                           \
        const float* p_ = lp + (size_t)(IT) * (16 * ZD_N);                      \
        _Pragma("unroll") for (int s = 0; s < 4; ++s) {                         \
            breg[s * 2 + 0] =                                                   \
                __builtin_nontemporal_load((const f32x4*)(p_ + s * 32));        \
            breg[s * 2 + 1] =                                                   \
                __builtin_nontemporal_load((const f32x4*)(p_ + s * 32 + 4));    \
        }                                                                       \
    }

    LOADI(0);
    for (int it = 0; it < 16; ++it) {
        // fp32 -> bf16 A-fragments for the 4 K=32 steps (consumes breg)
        s16x8 bfr[4];
#pragma unroll
        for (int s = 0; s < 4; ++s) {
            union { s16x8 v; __hip_bfloat162 b2[4]; } u;
            u.b2[0] = __float22bfloat162_rn(make_float2(breg[s*2][0],   breg[s*2][1]));
            u.b2[1] = __float22bfloat162_rn(make_float2(breg[s*2][2],   breg[s*2][3]));
            u.b2[2] = __float22bfloat162_rn(make_float2(breg[s*2+1][0], breg[s*2+1][1]));
            u.b2[3] = __float22bfloat162_rn(make_float2(breg[s*2+1][2], breg[s*2+1][3]));
            bfr[s] = u.v;
        }
        if (it + 1 < 16) LOADI(it + 1);  // prefetch overlaps MFMA + fold

        const int i0 = ibase + it * 16 + q * 4;    // this lane's C/D rows
        const float4 wsv = *(const float4*)&wlds[i0];

        f32x4 acc[8];
#pragma unroll
        for (int bt = 0; bt < 8; ++bt) acc[bt] = (f32x4)0.0f;
#pragma unroll
        for (int s = 0; s < 4; ++s) {
            const s16x8* zp = &zlds[(s * 4 + q) * 128 + l16];
#pragma unroll
            for (int bt = 0; bt < 8; ++bt)   // A = dwW frag, B = z frag
                acc[bt] = __builtin_amdgcn_mfma_f32_16x16x32_bf16(
                    bfr[s], zp[bt * 16], acc[bt], 0, 0, 0);
        }
        // C/D: col = l16 (= b, +bt*16), row = q*4 + r (= i_local).
        // fp32 fold + in-tile r-sum: pt[bt] += sum_r (T+w)[r] * x[b][i0+r]
#pragma unroll
        for (int bt = 0; bt < 8; ++bt) {
            const float4 xv = *(const float4*)(x + (size_t)(bt * 16 + l16) * IN_N + i0);
            pt[bt] += (acc[bt][0] + wsv.x) * xv.x
                    + (acc[bt][1] + wsv.y) * xv.y
                    + (acc[bt][2] + wsv.z) * xv.z
                    + (acc[bt][3] + wsv.w) * xv.w;
        }
    }
#undef LOADI

    // ---- reduce over i: across q-groups (i-partition is exact)
#pragma unroll
    for (int bt = 0; bt < 8; ++bt) {
        float s = pt[bt];
        s += __shfl_xor(s, 16, 64);
        s += __shfl_xor(s, 32, 64);
        if (lane < 16) red[w][bt * 16 + l16] = s;
    }
    __syncthreads();

    // ---- cross-wave combine + small terms (fp32 exact), one thread per b
    if (tid < B_N) {
        const int b = tid;
        float s = red[0][b] + red[1][b] + red[2][b] + red[3][b]
                + bbias[o] + dbb[o];
        const float* zr = z + (size_t)b * ZD_N;
        const float* dr = dbW + (size_t)o * ZD_N;
#pragma unroll 8
        for (int k = 0; k < ZD_N; k += 4) {
            float4 zv = *(const float4*)(zr + k);
            float4 dv = *(const float4*)(dr + k);
            s += zv.x * dv.x + zv.y * dv.y + zv.z * dv.z + zv.w * dv.w;
        }
        out[(size_t)b * OUT_N + o] = s;
    }
}

extern "C" void kernel_launch(void* const* d_in, const int* in_sizes, int n_in,
                              void* d_out, int out_size, void* d_ws, size_t ws_size,
                              hipStream_t stream) {
    hipLaunchKernelGGL(hyper_fused, dim3(OUT_N), dim3(256), 0, stream,
                       (const float*)d_in[0],  // x
                       (const float*)d_in[1],  // z
                       (const float*)d_in[2],  // base_weight
                       (const float*)d_in[3],  // dw_W
                       (const float*)d_in[4],  // dw_b
                       (const float*)d_in[5],  // base_bias
                       (const float*)d_in[6],  // db_W
                       (const float*)d_in[7],  // db_b
                       (float*)d_out);
}